// Round 10
// baseline (216.272 us; speedup 1.0000x reference)
//
#include <hip/hip_runtime.h>

typedef unsigned short u16;
typedef unsigned int   u32;
typedef float f32x4  __attribute__((ext_vector_type(4)));
typedef __bf16 bf16x8 __attribute__((ext_vector_type(8)));

__device__ __forceinline__ u16 f2bf(float f){
  u32 u = __float_as_uint(f);
  u += 0x7fffu + ((u >> 16) & 1u);          // RNE
  return (u16)(u >> 16);
}

// async global->LDS, 16B per lane; LDS dest is wave-uniform base + lane*16
__device__ __forceinline__ void gld16(const void* g, void* l){
  __builtin_amdgcn_global_load_lds((const __attribute__((address_space(1))) u32*)g,
                                   (__attribute__((address_space(3))) u32*)l, 16, 0, 0);
}

// ---------------- weight conversion: fp32->bf16, sigs->ternary bf16 ----------------
__global__ __launch_bounds__(256) void convert_kernel(
    const float* __restrict__ qw, const float* __restrict__ ow,
    const float* __restrict__ sg,
    u16* __restrict__ qwb, u16* __restrict__ owb, u16* __restrict__ sgb){
  int i = (blockIdx.x * 256 + threadIdx.x) * 4;   // 1,048,576 elements each
  f32x4 a = *(const f32x4*)(qw + i);
  f32x4 b = *(const f32x4*)(ow + i);
  f32x4 s = *(const f32x4*)(sg + i);
  uint2 pa, pb, ps;
  pa.x = (u32)f2bf(a[0]) | ((u32)f2bf(a[1]) << 16);
  pa.y = (u32)f2bf(a[2]) | ((u32)f2bf(a[3]) << 16);
  pb.x = (u32)f2bf(b[0]) | ((u32)f2bf(b[1]) << 16);
  pb.y = (u32)f2bf(b[2]) | ((u32)f2bf(b[3]) << 16);
  float t0 = (s[0] > 0.3f) ? 1.0f : ((s[0] < -0.3f) ? -1.0f : 0.0f);
  float t1 = (s[1] > 0.3f) ? 1.0f : ((s[1] < -0.3f) ? -1.0f : 0.0f);
  float t2 = (s[2] > 0.3f) ? 1.0f : ((s[2] < -0.3f) ? -1.0f : 0.0f);
  float t3 = (s[3] > 0.3f) ? 1.0f : ((s[3] < -0.3f) ? -1.0f : 0.0f);
  ps.x = (u32)f2bf(t0) | ((u32)f2bf(t1) << 16);
  ps.y = (u32)f2bf(t2) | ((u32)f2bf(t3) << 16);
  *(uint2*)(qwb + i) = pa;
  *(uint2*)(owb + i) = pb;
  *(uint2*)(sgb + i) = ps;
}

// ---------------- LayerNorm: one WAVE per token (no LDS, no barriers) ----------------
__global__ __launch_bounds__(256) void ln_kernel(
    const float* __restrict__ x, const float* __restrict__ g,
    const float* __restrict__ b, u16* __restrict__ xn){
  const int tid = threadIdx.x, lane = tid & 63, w = tid >> 6;
  const int t = blockIdx.x * 4 + w;
  const float* xr = x + (size_t)t * 1024;
  f32x4 v[4];
  #pragma unroll
  for (int j = 0; j < 4; ++j) v[j] = *(const f32x4*)(xr + j * 256 + lane * 4);
  float s = 0.f, ss = 0.f;
  #pragma unroll
  for (int j = 0; j < 4; ++j)
    #pragma unroll
    for (int e = 0; e < 4; ++e){ s += v[j][e]; ss += v[j][e] * v[j][e]; }
  #pragma unroll
  for (int off = 32; off; off >>= 1){
    s  += __shfl_xor(s, off);
    ss += __shfl_xor(ss, off);
  }
  float mean = s * (1.0f / 1024.0f);
  float var  = ss * (1.0f / 1024.0f) - mean * mean;   // jnp.var (ddof=0)
  float rs   = rsqrtf(var + 1e-5f);
  #pragma unroll
  for (int j = 0; j < 4; ++j){
    f32x4 gv = *(const f32x4*)(g + j * 256 + lane * 4);
    f32x4 bv = *(const f32x4*)(b + j * 256 + lane * 4);
    float y0 = (v[j][0]-mean)*rs*gv[0]+bv[0];
    float y1 = (v[j][1]-mean)*rs*gv[1]+bv[1];
    float y2 = (v[j][2]-mean)*rs*gv[2]+bv[2];
    float y3 = (v[j][3]-mean)*rs*gv[3]+bv[3];
    uint2 pk;
    pk.x = (u32)f2bf(y0) | ((u32)f2bf(y1) << 16);
    pk.y = (u32)f2bf(y2) | ((u32)f2bf(y3) << 16);
    *(uint2*)(xn + (size_t)t * 1024 + j * 256 + lane * 4) = pk;
  }
}

// ---------------- bf16 MFMA GEMM: C[m,n] = sum_k A[m,k]*B[n,k] (+epilogue) ----------------
// M=8192, N=1024, K=1024. 128x128 tile, 4 waves in 2x2, each wave 64x64 (4x4 MFMA 16x16x32).
// DOUBLE-BUFFERED LDS, stage(kt+1) after the barrier overlaps compute of kt.
// Grid = 512 1-D, XCD-swizzled. LDS XOR-swizzled (chunk g of row s at pos g^(s&7)).
// mode 0: outb[m,n] = bf16(C + bias[n]);  mode 1: outf[m,n] = C + bias[n] + resid[m,n]
__global__ __launch_bounds__(256, 2) void gemm_bt(
    const u16* __restrict__ A, const u16* __restrict__ B,
    const float* __restrict__ bias, const float* __restrict__ resid,
    float* __restrict__ outf, u16* __restrict__ outb, int mode){
  __shared__ u16 As[2][128 * 64];   // 2 x 16 KB
  __shared__ u16 Bs[2][128 * 64];
  const int tid = threadIdx.x;
  const int b = blockIdx.x;
  const int m0 = ((b & 7) * 8 + ((b >> 3) & 7)) * 128;   // XCD-contiguous m-stripe
  const int n0 = (b >> 6) * 128;
  const int w = tid >> 6, lane = tid & 63, lm = lane & 15, quad = lane >> 4;
  const int wm = (w & 1) * 64, wn = (w >> 1) * 64;
  const int lr = lane >> 3;                 // row-within-8 of this lane's staging chunk
  const int lg = (lane & 7) ^ lr;           // swizzled source chunk id
  const f32x4 fz = {0.f, 0.f, 0.f, 0.f};
  f32x4 acc[4][4];
  #pragma unroll
  for (int i = 0; i < 4; ++i)
    #pragma unroll
    for (int j = 0; j < 4; ++j) acc[i][j] = fz;

  const u16* gA = A + (size_t)(m0 + w * 32 + lr) * 1024 + lg * 8;
  const u16* gB = B + (size_t)(n0 + w * 32 + lr) * 1024 + lg * 8;
  const int lbase = (w * 32) * 64;          // wave-uniform LDS offset (u16)
  const int sw = lm & 7;

  auto stage = [&](int kt, int bb){
    #pragma unroll
    for (int sub = 0; sub < 4; ++sub){
      gld16(gA + (size_t)(sub * 8) * 1024 + kt * 64, &As[bb][lbase + sub * 8 * 64]);
      gld16(gB + (size_t)(sub * 8) * 1024 + kt * 64, &Bs[bb][lbase + sub * 8 * 64]);
    }
  };

  stage(0, 0);
  for (int kt = 0; kt < 16; ++kt){
    __syncthreads();                        // drains stage(kt); buffers now valid
    if (kt < 15) stage(kt + 1, (kt + 1) & 1);   // overlaps compute below
    const u16* as = As[kt & 1];
    const u16* bs = Bs[kt & 1];
    #pragma unroll
    for (int kk = 0; kk < 2; ++kk){
      const int ch = ((quad + kk * 4) ^ sw) * 8;   // swizzled chunk offset (u16)
      bf16x8 afr[4], bfr[4];
      #pragma unroll
      for (int i = 0; i < 4; ++i)
        afr[i] = *(const bf16x8*)(&as[(wm + i * 16 + lm) * 64 + ch]);
      #pragma unroll
      for (int j = 0; j < 4; ++j)
        bfr[j] = *(const bf16x8*)(&bs[(wn + j * 16 + lm) * 64 + ch]);
      #pragma unroll
      for (int i = 0; i < 4; ++i)
        #pragma unroll
        for (int j = 0; j < 4; ++j)
          acc[i][j] = __builtin_amdgcn_mfma_f32_16x16x32_bf16(afr[i], bfr[j], acc[i][j], 0, 0, 0);
    }
  }

  #pragma unroll
  for (int i = 0; i < 4; ++i){
    #pragma unroll
    for (int r = 0; r < 4; ++r){
      int grow = m0 + wm + i * 16 + quad * 4 + r;
      #pragma unroll
      for (int j = 0; j < 4; ++j){
        int gcol = n0 + wn + j * 16 + lm;
        float v = acc[i][j][r] + bias[gcol];
        if (mode){
          v += resid[(size_t)grow * 1024 + gcol];
          outf[(size_t)grow * 1024 + gcol] = v;
        } else {
          outb[(size_t)grow * 1024 + gcol] = f2bf(v);
        }
      }
    }
  }
}

// ---------------- fused scores + top2 + softmax + gather (zero-barrier, streaming) ----------------
// wave = 64 tokens x 1 head x ALL 1024 slots. block = 4 waves, same head ->
// concurrent waves hit the same 2KB sig tiles (L1 broadcast). grid (32, 16).
// 16x16x32 transposed MFMA: sig tile (16 slots) = A (streamed from global/L2,
// one contiguous 2KB region per tile, 2-deep register prefetch), q tokens = B
// (4 sets of 16, loaded once, 32 regs). NO LDS staging, NO barriers, NO DMA.
// Top-2 carries NO index state: full 10-bit slot id packed in the key's low
// mantissa bits (<=2^-13 rel, validated R2-R8) -> 3 VALU/score
// (v_and_or + v_med3 + v_max). Butterfly xor-16/32 leaves the merged result
// in ALL lanes; lane L selects set=quad -> its own token t0+L. Epilogue
// (expf, V-gather, store) is lane-private.
__global__ __launch_bounds__(256) void route3_kernel(
    const u16* __restrict__ q, const u16* __restrict__ sig,
    const float* __restrict__ V, const float* __restrict__ temp,
    u16* __restrict__ rd){
  const int h = blockIdx.y;
  const int tid = threadIdx.x, w = tid >> 6, lane = tid & 63;
  const int lm = lane & 15, quad = lane >> 4;
  const int t0 = blockIdx.x * 256 + w * 64;

  // q B-frags (loop-invariant): set s -> token t0+s*16+lm; k = quad*8+j, +32
  bf16x8 qf[4][2];
  #pragma unroll
  for (int s = 0; s < 4; ++s){
    const u16* qp = q + (size_t)(t0 + s * 16 + lm) * 1024 + h * 64 + quad * 8;
    qf[s][0] = *(const bf16x8*)(qp);
    qf[s][1] = *(const bf16x8*)(qp + 32);
  }

  // sig A-frag stream: tile t = slots [t*16, t*16+16); lane reads
  // sig[(t*16+lm)*64 + quad*8] (k 0..31) and +32 (k 32..63).
  const u16* sp = sig + (size_t)h * 65536 + lm * 64 + quad * 8;
  bf16x8 c0 = *(const bf16x8*)(sp);
  bf16x8 c1 = *(const bf16x8*)(sp + 32);
  bf16x8 n0 = *(const bf16x8*)(sp + 1024);
  bf16x8 n1 = *(const bf16x8*)(sp + 1024 + 32);
  sp += 2048;                               // points at tile 2

  const f32x4 fz = {0.f, 0.f, 0.f, 0.f};
  const u32 MASK = 0xFFFFFC00u;
  float v1[4], v2[4];
  #pragma unroll
  for (int s = 0; s < 4; ++s){ v1[s] = -3.0e38f; v2[s] = -3.0e38f; }
  u32 rk0 = (u32)(quad * 4), rk1 = rk0 + 1, rk2 = rk0 + 2, rk3 = rk0 + 3;

  for (int t = 0; t < 64; ++t){
    #pragma unroll
    for (int s = 0; s < 4; ++s){
      f32x4 acc = __builtin_amdgcn_mfma_f32_16x16x32_bf16(c0, qf[s][0], fz, 0, 0, 0);
      acc       = __builtin_amdgcn_mfma_f32_16x16x32_bf16(c1, qf[s][1], acc, 0, 0, 0);
      float k0 = __uint_as_float((__float_as_uint(acc[0]) & MASK) | rk0);
      float k1 = __uint_as_float((__float_as_uint(acc[1]) & MASK) | rk1);
      float k2 = __uint_as_float((__float_as_uint(acc[2]) & MASK) | rk2);
      float k3 = __uint_as_float((__float_as_uint(acc[3]) & MASK) | rk3);
      float o;
      o = v1[s]; v1[s] = fmaxf(o, k0); v2[s] = __builtin_amdgcn_fmed3f(o, v2[s], k0);
      o = v1[s]; v1[s] = fmaxf(o, k1); v2[s] = __builtin_amdgcn_fmed3f(o, v2[s], k1);
      o = v1[s]; v1[s] = fmaxf(o, k2); v2[s] = __builtin_amdgcn_fmed3f(o, v2[s], k2);
      o = v1[s]; v1[s] = fmaxf(o, k3); v2[s] = __builtin_amdgcn_fmed3f(o, v2[s], k3);
    }
    c0 = n0; c1 = n1;
    if (t < 62){
      n0 = *(const bf16x8*)(sp);
      n1 = *(const bf16x8*)(sp + 32);
      sp += 1024;
    }
    rk0 += 16u; rk1 += 16u; rk2 += 16u; rk3 += 16u;
  }

  // butterfly merge across quads (xor 16, 32): slot ids disjoint per quad,
  // result identical in all lanes of a column group
  #pragma unroll
  for (int off = 16; off <= 32; off <<= 1){
    #pragma unroll
    for (int s = 0; s < 4; ++s){
      float o1 = __shfl_xor(v1[s], off);
      float o2 = __shfl_xor(v2[s], off);
      float ov = v1[s];
      v1[s] = fmaxf(ov, o1);
      v2[s] = __builtin_amdgcn_fmed3f(ov, o1, fmaxf(v2[s], o2));
    }
  }

  // lane L owns token t0 + L  (set = quad, column = lm)
  float a1 = (quad & 1) ? v1[1] : v1[0], b1 = (quad & 1) ? v1[3] : v1[2];
  float a2 = (quad & 1) ? v2[1] : v2[0], b2 = (quad & 1) ? v2[3] : v2[2];
  float V1 = (quad & 2) ? b1 : a1;
  float V2 = (quad & 2) ? b2 : a2;
  u32 u1 = __float_as_uint(V1), u2 = __float_as_uint(V2);
  int I1 = (int)(u1 & 1023u), I2 = (int)(u2 & 1023u);
  float s1 = __uint_as_float(u1 & MASK);
  float s2 = __uint_as_float(u2 & MASK);
  float tsc = 1.0f / (temp[0] * 8.0f);       // 1/(temperature*sqrt(64))
  float ex = __expf((s2 - s1) * tsc);        // <= 1, stable
  float iw = 1.0f / (1.0f + ex);
  float W1 = iw, W2 = ex * iw;

  // gather: lane-private, 64 dims
  const float* va = V + ((size_t)h * 1024 + I1) * 64;
  const float* vb = V + ((size_t)h * 1024 + I2) * 64;
  u16* dst = rd + (size_t)(t0 + lane) * 1024 + h * 64;
  #pragma unroll
  for (int g = 0; g < 4; ++g){
    f32x4 xa = *(const f32x4*)(va + g * 16);
    f32x4 xb = *(const f32x4*)(va + g * 16 + 4);
    f32x4 xc = *(const f32x4*)(va + g * 16 + 8);
    f32x4 xd = *(const f32x4*)(va + g * 16 + 12);
    f32x4 ya = *(const f32x4*)(vb + g * 16);
    f32x4 yb = *(const f32x4*)(vb + g * 16 + 4);
    f32x4 yc = *(const f32x4*)(vb + g * 16 + 8);
    f32x4 yd = *(const f32x4*)(vb + g * 16 + 12);
    uint4 o;
    o.x = (u32)f2bf(W1*xa[0]+W2*ya[0]) | ((u32)f2bf(W1*xa[1]+W2*ya[1]) << 16);
    o.y = (u32)f2bf(W1*xa[2]+W2*ya[2]) | ((u32)f2bf(W1*xa[3]+W2*ya[3]) << 16);
    o.z = (u32)f2bf(W1*xb[0]+W2*yb[0]) | ((u32)f2bf(W1*xb[1]+W2*yb[1]) << 16);
    o.w = (u32)f2bf(W1*xb[2]+W2*yb[2]) | ((u32)f2bf(W1*xb[3]+W2*yb[3]) << 16);
    uint4 p;
    p.x = (u32)f2bf(W1*xc[0]+W2*yc[0]) | ((u32)f2bf(W1*xc[1]+W2*yc[1]) << 16);
    p.y = (u32)f2bf(W1*xc[2]+W2*yc[2]) | ((u32)f2bf(W1*xc[3]+W2*yc[3]) << 16);
    p.z = (u32)f2bf(W1*xd[0]+W2*yd[0]) | ((u32)f2bf(W1*xd[1]+W2*yd[1]) << 16);
    p.w = (u32)f2bf(W1*xd[2]+W2*yd[2]) | ((u32)f2bf(W1*xd[3]+W2*yd[3]) << 16);
    *(uint4*)(dst + g * 16) = o;
    *(uint4*)(dst + g * 16 + 8) = p;
  }
}

extern "C" void kernel_launch(void* const* d_in, const int* in_sizes, int n_in,
                              void* d_out, int out_size, void* d_ws, size_t ws_size,
                              hipStream_t stream){
  const float* x    = (const float*)d_in[0];
  const float* lng  = (const float*)d_in[1];
  const float* lnb  = (const float*)d_in[2];
  const float* qw   = (const float*)d_in[3];
  const float* qb   = (const float*)d_in[4];
  const float* sig  = (const float*)d_in[5];
  const float* sv   = (const float*)d_in[6];
  const float* ow   = (const float*)d_in[7];
  const float* ob   = (const float*)d_in[8];
  const float* temp = (const float*)d_in[9];
  float* out = (float*)d_out;

  char* ws = (char*)d_ws;
  u16* xn   = (u16*)(ws);                                  // 16 MiB  (x_norm bf16; reused as `read`)
  u16* qwb  = (u16*)(ws + 16777216);                       //  2 MiB
  u16* owb  = (u16*)(ws + 16777216 + 2097152);             //  2 MiB
  u16* sgb  = (u16*)(ws + 16777216 + 2 * 2097152);         //  2 MiB
  u16* qb16 = (u16*)(ws + 16777216 + 3 * 2097152);         // 16 MiB  (q bf16)
  u16* rdb  = xn;                                          // alias: x_norm dead after GEMM1

  convert_kernel<<<1024, 256, 0, stream>>>(qw, ow, sig, qwb, owb, sgb);
  ln_kernel<<<2048, 256, 0, stream>>>(x, lng, lnb, xn);
  gemm_bt<<<512, 256, 0, stream>>>(xn, qwb, qb, nullptr, nullptr, qb16, 0);
  route3_kernel<<<dim3(32, 16), 256, 0, stream>>>(qb16, sgb, sv, temp, rdb);
  gemm_bt<<<512, 256, 0, stream>>>(rdb, owb, ob, x, out, nullptr, 1);
}

// Round 11
// 215.043 us; speedup vs baseline: 1.0057x; 1.0057x over previous
//
#include <hip/hip_runtime.h>

typedef unsigned short u16;
typedef unsigned int   u32;
typedef float f32x4  __attribute__((ext_vector_type(4)));
typedef __bf16 bf16x8 __attribute__((ext_vector_type(8)));

__device__ __forceinline__ u16 f2bf(float f){
  u32 u = __float_as_uint(f);
  u += 0x7fffu + ((u >> 16) & 1u);          // RNE
  return (u16)(u >> 16);
}

// async global->LDS, 16B per lane; LDS dest is wave-uniform base + lane*16
__device__ __forceinline__ void gld16(const void* g, void* l){
  __builtin_amdgcn_global_load_lds((const __attribute__((address_space(1))) u32*)g,
                                   (__attribute__((address_space(3))) u32*)l, 16, 0, 0);
}

// ---------------- fused convert (blocks 0..1023) + LayerNorm (blocks 1024..3071) ----------------
__global__ __launch_bounds__(256) void prep_kernel(
    const float* __restrict__ x, const float* __restrict__ lng,
    const float* __restrict__ lnb, const float* __restrict__ qw,
    const float* __restrict__ ow, const float* __restrict__ sg,
    u16* __restrict__ xn, u16* __restrict__ qwb,
    u16* __restrict__ owb, u16* __restrict__ sgb){
  const int b = blockIdx.x, tid = threadIdx.x;
  if (b < 1024){
    int i = (b * 256 + tid) * 4;            // 1,048,576 elements each
    f32x4 a = *(const f32x4*)(qw + i);
    f32x4 c = *(const f32x4*)(ow + i);
    f32x4 s = *(const f32x4*)(sg + i);
    uint2 pa, pb, ps;
    pa.x = (u32)f2bf(a[0]) | ((u32)f2bf(a[1]) << 16);
    pa.y = (u32)f2bf(a[2]) | ((u32)f2bf(a[3]) << 16);
    pb.x = (u32)f2bf(c[0]) | ((u32)f2bf(c[1]) << 16);
    pb.y = (u32)f2bf(c[2]) | ((u32)f2bf(c[3]) << 16);
    float t0 = (s[0] > 0.3f) ? 1.0f : ((s[0] < -0.3f) ? -1.0f : 0.0f);
    float t1 = (s[1] > 0.3f) ? 1.0f : ((s[1] < -0.3f) ? -1.0f : 0.0f);
    float t2 = (s[2] > 0.3f) ? 1.0f : ((s[2] < -0.3f) ? -1.0f : 0.0f);
    float t3 = (s[3] > 0.3f) ? 1.0f : ((s[3] < -0.3f) ? -1.0f : 0.0f);
    ps.x = (u32)f2bf(t0) | ((u32)f2bf(t1) << 16);
    ps.y = (u32)f2bf(t2) | ((u32)f2bf(t3) << 16);
    *(uint2*)(qwb + i) = pa;
    *(uint2*)(owb + i) = pb;
    *(uint2*)(sgb + i) = ps;
  } else {
    const int lane = tid & 63, w = tid >> 6;
    const int t = (b - 1024) * 4 + w;       // one wave per token, no LDS/barrier
    const float* xr = x + (size_t)t * 1024;
    f32x4 v[4];
    #pragma unroll
    for (int j = 0; j < 4; ++j) v[j] = *(const f32x4*)(xr + j * 256 + lane * 4);
    float s = 0.f, ss = 0.f;
    #pragma unroll
    for (int j = 0; j < 4; ++j)
      #pragma unroll
      for (int e = 0; e < 4; ++e){ s += v[j][e]; ss += v[j][e] * v[j][e]; }
    #pragma unroll
    for (int off = 32; off; off >>= 1){
      s  += __shfl_xor(s, off);
      ss += __shfl_xor(ss, off);
    }
    float mean = s * (1.0f / 1024.0f);
    float var  = ss * (1.0f / 1024.0f) - mean * mean;   // jnp.var (ddof=0)
    float rs   = rsqrtf(var + 1e-5f);
    #pragma unroll
    for (int j = 0; j < 4; ++j){
      f32x4 gv = *(const f32x4*)(lng + j * 256 + lane * 4);
      f32x4 bv = *(const f32x4*)(lnb + j * 256 + lane * 4);
      float y0 = (v[j][0]-mean)*rs*gv[0]+bv[0];
      float y1 = (v[j][1]-mean)*rs*gv[1]+bv[1];
      float y2 = (v[j][2]-mean)*rs*gv[2]+bv[2];
      float y3 = (v[j][3]-mean)*rs*gv[3]+bv[3];
      uint2 pk;
      pk.x = (u32)f2bf(y0) | ((u32)f2bf(y1) << 16);
      pk.y = (u32)f2bf(y2) | ((u32)f2bf(y3) << 16);
      *(uint2*)(xn + (size_t)t * 1024 + j * 256 + lane * 4) = pk;
    }
  }
}

// ---------------- bf16 MFMA GEMM: C[m,n] = sum_k A[m,k]*B[n,k] (+epilogue) ----------------
// M=8192, N=1024, K=1024. 128x128 tile, 4 waves in 2x2, each wave 64x64 (4x4 MFMA 16x16x32).
// DOUBLE-BUFFERED LDS, stage(kt+1) after the barrier overlaps compute of kt.
// Grid = 512 1-D, XCD-swizzled. LDS XOR-swizzled (chunk g of row s at pos g^(s&7)).
// mode 0: outb[m,n] = bf16(C + bias[n]);  mode 1: outf[m,n] = C + bias[n] + resid[m,n]
__global__ __launch_bounds__(256, 2) void gemm_bt(
    const u16* __restrict__ A, const u16* __restrict__ B,
    const float* __restrict__ bias, const float* __restrict__ resid,
    float* __restrict__ outf, u16* __restrict__ outb, int mode){
  __shared__ u16 As[2][128 * 64];   // 2 x 16 KB
  __shared__ u16 Bs[2][128 * 64];
  const int tid = threadIdx.x;
  const int b = blockIdx.x;
  const int m0 = ((b & 7) * 8 + ((b >> 3) & 7)) * 128;   // XCD-contiguous m-stripe
  const int n0 = (b >> 6) * 128;
  const int w = tid >> 6, lane = tid & 63, lm = lane & 15, quad = lane >> 4;
  const int wm = (w & 1) * 64, wn = (w >> 1) * 64;
  const int lr = lane >> 3;                 // row-within-8 of this lane's staging chunk
  const int lg = (lane & 7) ^ lr;           // swizzled source chunk id
  const f32x4 fz = {0.f, 0.f, 0.f, 0.f};
  f32x4 acc[4][4];
  #pragma unroll
  for (int i = 0; i < 4; ++i)
    #pragma unroll
    for (int j = 0; j < 4; ++j) acc[i][j] = fz;

  const u16* gA = A + (size_t)(m0 + w * 32 + lr) * 1024 + lg * 8;
  const u16* gB = B + (size_t)(n0 + w * 32 + lr) * 1024 + lg * 8;
  const int lbase = (w * 32) * 64;          // wave-uniform LDS offset (u16)
  const int sw = lm & 7;

  auto stage = [&](int kt, int bb){
    #pragma unroll
    for (int sub = 0; sub < 4; ++sub){
      gld16(gA + (size_t)(sub * 8) * 1024 + kt * 64, &As[bb][lbase + sub * 8 * 64]);
      gld16(gB + (size_t)(sub * 8) * 1024 + kt * 64, &Bs[bb][lbase + sub * 8 * 64]);
    }
  };

  stage(0, 0);
  for (int kt = 0; kt < 16; ++kt){
    __syncthreads();                        // drains stage(kt); buffers now valid
    if (kt < 15) stage(kt + 1, (kt + 1) & 1);   // overlaps compute below
    const u16* as = As[kt & 1];
    const u16* bs = Bs[kt & 1];
    #pragma unroll
    for (int kk = 0; kk < 2; ++kk){
      const int ch = ((quad + kk * 4) ^ sw) * 8;   // swizzled chunk offset (u16)
      bf16x8 afr[4], bfr[4];
      #pragma unroll
      for (int i = 0; i < 4; ++i)
        afr[i] = *(const bf16x8*)(&as[(wm + i * 16 + lm) * 64 + ch]);
      #pragma unroll
      for (int j = 0; j < 4; ++j)
        bfr[j] = *(const bf16x8*)(&bs[(wn + j * 16 + lm) * 64 + ch]);
      #pragma unroll
      for (int i = 0; i < 4; ++i)
        #pragma unroll
        for (int j = 0; j < 4; ++j)
          acc[i][j] = __builtin_amdgcn_mfma_f32_16x16x32_bf16(afr[i], bfr[j], acc[i][j], 0, 0, 0);
    }
  }

  #pragma unroll
  for (int i = 0; i < 4; ++i){
    #pragma unroll
    for (int r = 0; r < 4; ++r){
      int grow = m0 + wm + i * 16 + quad * 4 + r;
      #pragma unroll
      for (int j = 0; j < 4; ++j){
        int gcol = n0 + wn + j * 16 + lm;
        float v = acc[i][j][r] + bias[gcol];
        if (mode){
          v += resid[(size_t)grow * 1024 + gcol];
          outf[(size_t)grow * 1024 + gcol] = v;
        } else {
          outb[(size_t)grow * 1024 + gcol] = f2bf(v);
        }
      }
    }
  }
}

// ---------------- fused scores + top2 + softmax + gather (split-slot streaming) ----------------
// block = 4 waves x 128 tokens x 1 head; grid (64,16) = 4096 waves -> 4/SIMD
// (R10's grid of 2048 waves capped occupancy at 2/SIMD = latency-bound).
// Wave (g=w>>1, s=w&1): token group g (64 tokens), slot half s (512 slots,
// 32 tiles of 16). Sig streamed straight from global/L2 (2KB contiguous per
// tile, 2-deep register prefetch, no LDS staging, no DMA, no barrier in loop).
// Top-2 keys carry the FULL 10-bit slot id in low mantissa bits (<=2^-13 rel,
// validated R2+): 3 VALU/score, 3-op merges. One barrier total: 2-half LDS
// merge (3 ops), then 2 threads/token epilogue (expf + V-gather + store).
__global__ __launch_bounds__(256) void route3_kernel(
    const u16* __restrict__ q, const u16* __restrict__ sig,
    const float* __restrict__ V, const float* __restrict__ temp,
    u16* __restrict__ rd){
  const int h = blockIdx.y;
  const int tid = threadIdx.x, w = tid >> 6, lane = tid & 63;
  const int lm = lane & 15, quad = lane >> 4;
  const int s = w & 1, g = w >> 1;
  const int t0 = blockIdx.x * 128 + g * 64;

  __shared__ float sv[2][2][64][2];         // [g][s][lane][{V1,V2}]  (2 KB)

  // q B-frags (loop-invariant): set st -> token t0+st*16+lm; k = quad*8+j, +32
  bf16x8 qf[4][2];
  #pragma unroll
  for (int st = 0; st < 4; ++st){
    const u16* qp = q + (size_t)(t0 + st * 16 + lm) * 1024 + h * 64 + quad * 8;
    qf[st][0] = *(const bf16x8*)(qp);
    qf[st][1] = *(const bf16x8*)(qp + 32);
  }

  // sig A-frag stream over this wave's half: tile t = slots s*512 + [t*16,+16)
  const u16* sp = sig + (size_t)h * 65536 + (size_t)(s * 512 + lm) * 64 + quad * 8;
  bf16x8 c0 = *(const bf16x8*)(sp);
  bf16x8 c1 = *(const bf16x8*)(sp + 32);
  bf16x8 n0 = *(const bf16x8*)(sp + 1024);
  bf16x8 n1 = *(const bf16x8*)(sp + 1024 + 32);
  sp += 2048;                               // points at tile 2

  const f32x4 fz = {0.f, 0.f, 0.f, 0.f};
  const u32 MASK = 0xFFFFFC00u;
  float v1[4], v2[4];
  #pragma unroll
  for (int st = 0; st < 4; ++st){ v1[st] = -3.0e38f; v2[st] = -3.0e38f; }
  u32 rk0 = (u32)(s * 512 + quad * 4), rk1 = rk0 + 1, rk2 = rk0 + 2, rk3 = rk0 + 3;

  for (int t = 0; t < 32; ++t){
    #pragma unroll
    for (int st = 0; st < 4; ++st){
      f32x4 acc = __builtin_amdgcn_mfma_f32_16x16x32_bf16(c0, qf[st][0], fz, 0, 0, 0);
      acc       = __builtin_amdgcn_mfma_f32_16x16x32_bf16(c1, qf[st][1], acc, 0, 0, 0);
      float k0 = __uint_as_float((__float_as_uint(acc[0]) & MASK) | rk0);
      float k1 = __uint_as_float((__float_as_uint(acc[1]) & MASK) | rk1);
      float k2 = __uint_as_float((__float_as_uint(acc[2]) & MASK) | rk2);
      float k3 = __uint_as_float((__float_as_uint(acc[3]) & MASK) | rk3);
      float o;
      o = v1[st]; v1[st] = fmaxf(o, k0); v2[st] = __builtin_amdgcn_fmed3f(o, v2[st], k0);
      o = v1[st]; v1[st] = fmaxf(o, k1); v2[st] = __builtin_amdgcn_fmed3f(o, v2[st], k1);
      o = v1[st]; v1[st] = fmaxf(o, k2); v2[st] = __builtin_amdgcn_fmed3f(o, v2[st], k2);
      o = v1[st]; v1[st] = fmaxf(o, k3); v2[st] = __builtin_amdgcn_fmed3f(o, v2[st], k3);
    }
    c0 = n0; c1 = n1;
    if (t < 30){
      n0 = *(const bf16x8*)(sp);
      n1 = *(const bf16x8*)(sp + 32);
      sp += 1024;
    }
    rk0 += 16u; rk1 += 16u; rk2 += 16u; rk3 += 16u;
  }

  // butterfly merge across quads (xor 16, 32): slot ids disjoint per quad
  #pragma unroll
  for (int off = 16; off <= 32; off <<= 1){
    #pragma unroll
    for (int st = 0; st < 4; ++st){
      float o1 = __shfl_xor(v1[st], off);
      float o2 = __shfl_xor(v2[st], off);
      float ov = v1[st];
      v1[st] = fmaxf(ov, o1);
      v2[st] = __builtin_amdgcn_fmed3f(ov, o1, fmaxf(v2[st], o2));
    }
  }

  // lane L owns token t0 + L within this half (set = quad)
  {
    float a1 = (quad & 1) ? v1[1] : v1[0], b1 = (quad & 1) ? v1[3] : v1[2];
    float a2 = (quad & 1) ? v2[1] : v2[0], b2 = (quad & 1) ? v2[3] : v2[2];
    sv[g][s][lane][0] = (quad & 2) ? b1 : a1;
    sv[g][s][lane][1] = (quad & 2) ? b2 : a2;
  }
  __syncthreads();

  // epilogue: 2 threads per token; thread (tk, hd) does dims [hd*32, +32)
  const int tk = tid >> 1, hd = tid & 1;    // tk 0..127
  const int gg = tk >> 6, ll = tk & 63;
  float a1 = sv[gg][0][ll][0], a2 = sv[gg][0][ll][1];
  float b1 = sv[gg][1][ll][0], b2 = sv[gg][1][ll][1];
  float V1 = fmaxf(a1, b1);
  float V2 = __builtin_amdgcn_fmed3f(a1, b1, fmaxf(a2, b2));
  u32 u1 = __float_as_uint(V1), u2 = __float_as_uint(V2);
  int I1 = (int)(u1 & 1023u), I2 = (int)(u2 & 1023u);
  float s1 = __uint_as_float(u1 & MASK);
  float s2 = __uint_as_float(u2 & MASK);
  float tsc = 1.0f / (temp[0] * 8.0f);       // 1/(temperature*sqrt(64))
  float ex = __expf((s2 - s1) * tsc);        // <= 1, stable
  float iw = 1.0f / (1.0f + ex);
  float W1 = iw, W2 = ex * iw;

  const float* va = V + ((size_t)h * 1024 + I1) * 64 + hd * 32;
  const float* vb = V + ((size_t)h * 1024 + I2) * 64 + hd * 32;
  u16* dst = rd + (size_t)(blockIdx.x * 128 + tk) * 1024 + h * 64 + hd * 32;
  #pragma unroll
  for (int gr = 0; gr < 2; ++gr){
    f32x4 xa = *(const f32x4*)(va + gr * 16);
    f32x4 xb = *(const f32x4*)(va + gr * 16 + 4);
    f32x4 xc = *(const f32x4*)(va + gr * 16 + 8);
    f32x4 xd = *(const f32x4*)(va + gr * 16 + 12);
    f32x4 ya = *(const f32x4*)(vb + gr * 16);
    f32x4 yb = *(const f32x4*)(vb + gr * 16 + 4);
    f32x4 yc = *(const f32x4*)(vb + gr * 16 + 8);
    f32x4 yd = *(const f32x4*)(vb + gr * 16 + 12);
    uint4 o;
    o.x = (u32)f2bf(W1*xa[0]+W2*ya[0]) | ((u32)f2bf(W1*xa[1]+W2*ya[1]) << 16);
    o.y = (u32)f2bf(W1*xa[2]+W2*ya[2]) | ((u32)f2bf(W1*xa[3]+W2*ya[3]) << 16);
    o.z = (u32)f2bf(W1*xb[0]+W2*yb[0]) | ((u32)f2bf(W1*xb[1]+W2*yb[1]) << 16);
    o.w = (u32)f2bf(W1*xb[2]+W2*yb[2]) | ((u32)f2bf(W1*xb[3]+W2*yb[3]) << 16);
    uint4 p;
    p.x = (u32)f2bf(W1*xc[0]+W2*yc[0]) | ((u32)f2bf(W1*xc[1]+W2*yc[1]) << 16);
    p.y = (u32)f2bf(W1*xc[2]+W2*yc[2]) | ((u32)f2bf(W1*xc[3]+W2*yc[3]) << 16);
    p.z = (u32)f2bf(W1*xd[0]+W2*yd[0]) | ((u32)f2bf(W1*xd[1]+W2*yd[1]) << 16);
    p.w = (u32)f2bf(W1*xd[2]+W2*yd[2]) | ((u32)f2bf(W1*xd[3]+W2*yd[3]) << 16);
    *(uint4*)(dst + gr * 16) = o;
    *(uint4*)(dst + gr * 16 + 8) = p;
  }
}

extern "C" void kernel_launch(void* const* d_in, const int* in_sizes, int n_in,
                              void* d_out, int out_size, void* d_ws, size_t ws_size,
                              hipStream_t stream){
  const float* x    = (const float*)d_in[0];
  const float* lng  = (const float*)d_in[1];
  const float* lnb  = (const float*)d_in[2];
  const float* qw   = (const float*)d_in[3];
  const float* qb   = (const float*)d_in[4];
  const float* sig  = (const float*)d_in[5];
  const float* sv   = (const float*)d_in[6];
  const float* ow   = (const float*)d_in[7];
  const float* ob   = (const float*)d_in[8];
  const float* temp = (const float*)d_in[9];
  float* out = (float*)d_out;

  char* ws = (char*)d_ws;
  u16* xn   = (u16*)(ws);                                  // 16 MiB  (x_norm bf16; reused as `read`)
  u16* qwb  = (u16*)(ws + 16777216);                       //  2 MiB
  u16* owb  = (u16*)(ws + 16777216 + 2097152);             //  2 MiB
  u16* sgb  = (u16*)(ws + 16777216 + 2 * 2097152);         //  2 MiB
  u16* qb16 = (u16*)(ws + 16777216 + 3 * 2097152);         // 16 MiB  (q bf16)
  u16* rdb  = xn;                                          // alias: x_norm dead after GEMM1

  prep_kernel<<<3072, 256, 0, stream>>>(x, lng, lnb, qw, ow, sig, xn, qwb, owb, sgb);
  gemm_bt<<<512, 256, 0, stream>>>(xn, qwb, qb, nullptr, nullptr, qb16, 0);
  route3_kernel<<<dim3(64, 16), 256, 0, stream>>>(qb16, sgb, sv, temp, rdb);
  gemm_bt<<<512, 256, 0, stream>>>(rdb, owb, ob, x, out, nullptr, 1);
}